// Round 3
// baseline (553.724 us; speedup 1.0000x reference)
//
#include <hip/hip_runtime.h>
#include <hip/hip_bf16.h>
#include <math.h>

#define NQ 300
#define BSZ 8
#define DIM 256
#define NHEAD 8
#define ROWS (NQ * BSZ)  // 2400

typedef __attribute__((ext_vector_type(8))) short bf16x8;
typedef __attribute__((ext_vector_type(4))) float f32x4;

__device__ inline short f2bf(float f) {
  __hip_bfloat16 h = __float2bfloat16(f);
  return *reinterpret_cast<short*>(&h);
}
__device__ inline float bf2f(unsigned short u) {
  union { unsigned u; float f; } c;
  c.u = ((unsigned)u) << 16;
  return c.f;
}

// ---------------- elementwise add (float4) ----------------
__global__ __launch_bounds__(256) void add4_kernel(const float4* __restrict__ a,
                                                   const float4* __restrict__ b,
                                                   float4* __restrict__ o, int n4) {
  int i = blockIdx.x * 256 + threadIdx.x;
  if (i < n4) {
    float4 x = a[i], y = b[i];
    o[i] = make_float4(x.x + y.x, x.y + y.y, x.z + y.z, x.w + y.w);
  }
}

// ---------------- one-shot weight conversion fp32 -> bf16, swizzled tiles ----------------
// Layout: tiles of BN=64 rows x 256 K. tile(nb,c) at ((nb*(K/256)+c)*64 rows)*512B.
// Within tile: byte(rr, k) = rr*512 + ((k/8)*16 ^ ((rr&7)<<4)) + (k%8)*2.
// GEMM stages a tile with a LINEAR copy and reads with the same XOR (rule #21).
struct WEntry {
  const float* src;
  unsigned short* dst;
  int K;
  int gstart;  // first granule (granule = 8 elements = 16B)
};
struct WPack {
  WEntry e[8];
  int total;
};
__global__ __launch_bounds__(256) void wconv_kernel(WPack P) {
  int g = blockIdx.x * 256 + threadIdx.x;
  if (g >= P.total) return;
  int i = 0;
  while (i < 7 && g >= P.e[i + 1].gstart) ++i;
  const float* src = P.e[i].src;
  unsigned short* dst = P.e[i].dst;
  const int K = P.e[i].K;
  int gl = g - P.e[i].gstart;
  int gpr = K >> 3;            // granules per row
  int r = gl / gpr, gk = gl - r * gpr;
  int nb = r >> 6, rr = r & 63;
  int c = gk >> 5, gi = gk & 31;
  const float* s = src + (size_t)r * K + gk * 8;
  float4 v0 = *(const float4*)s, v1 = *(const float4*)(s + 4);
  bf16x8 o;
  o[0] = f2bf(v0.x); o[1] = f2bf(v0.y); o[2] = f2bf(v0.z); o[3] = f2bf(v0.w);
  o[4] = f2bf(v1.x); o[5] = f2bf(v1.y); o[6] = f2bf(v1.z); o[7] = f2bf(v1.w);
  size_t byte = ((size_t)(nb * (K >> 8) + c) * 64 + rr) * 512 + ((gi * 16) ^ ((rr & 7) << 4));
  *(bf16x8*)((char*)dst + byte) = o;
}

// ---------------- bf16 MFMA GEMM, B-once staging + A direct-to-reg ----------------
// C[M][N] = A[M][K](fp32) @ W[N][K]^T + bias. W pre-converted/swizzled (Wz).
// 256 threads = 4 waves (2x2). BN=64 fixed; per chunk of 256 K: stage B tile (32KB,
// linear), single barrier, then 8 barrier-free MFMA substeps with A global->reg.
// mfma_f32_16x16x32_bf16 C/D: col=lane&15, row=(lane>>4)*4+reg  [m89-verified]
template <int BM, bool RELU, bool VMASK, bool OBF16>
__global__ __launch_bounds__(256) void mgemm2(const float* __restrict__ A,
                                              const unsigned short* __restrict__ Wz,
                                              const float* __restrict__ bias,
                                              void* __restrict__ C, int M, int N, int K,
                                              const unsigned char* __restrict__ vmask,
                                              int Srows) {
  constexpr int WMT = BM / 2;
  constexpr int AM = WMT / 16;
  __shared__ char Bs[32768];
  const int tid = threadIdx.x, lane = tid & 63, wid = tid >> 6;
  const int wr = wid >> 1, wc = wid & 1;
  const int nb = blockIdx.x;
  const int m0 = blockIdx.y * BM;
  const int l15 = lane & 15, lk = lane >> 4;

  f32x4 acc[AM][2];
#pragma unroll
  for (int i = 0; i < AM; ++i)
#pragma unroll
    for (int j = 0; j < 2; ++j) acc[i][j] = {0.f, 0.f, 0.f, 0.f};

  const int nchunk = K >> 8;
  const unsigned short* wt = Wz + (size_t)nb * nchunk * 16384;

  const float* aptr[AM];
#pragma unroll
  for (int i = 0; i < AM; ++i) {
    int row = m0 + wr * WMT + i * 16 + l15;
    if (row > M - 1) row = M - 1;  // clamped rows only feed discarded outputs
    aptr[i] = A + (size_t)row * K + lk * 8;
  }

  // precomputed swizzled B read offsets (j=0,1), substep adds s*64 to granule byte
  int bbyte[2];
#pragma unroll
  for (int j = 0; j < 2; ++j) {
    int rr = wc * 32 + j * 16 + l15;
    bbyte[j] = rr * 512 + ((lk * 16) ^ ((rr & 7) << 4));
  }
  const int swzmask = 0;  // (doc) XOR already folded into bbyte; s*64 toggles bit6 which
                          // the XOR (bits 4-6) also touches -> must re-apply per substep.

  for (int c = 0; c < nchunk; ++c) {
    __syncthreads();
    const float4* src = (const float4*)(wt + c * 16384);
#pragma unroll
    for (int i = 0; i < 8; ++i) ((float4*)Bs)[tid + i * 256] = src[tid + i * 256];
    __syncthreads();
#pragma unroll
    for (int s = 0; s < 8; ++s) {
      bf16x8 af[AM], bfr[2];
#pragma unroll
      for (int i = 0; i < AM; ++i) {
        const float* p = aptr[i] + c * 256 + s * 32;
        float4 v0 = *(const float4*)p, v1 = *(const float4*)(p + 4);
        bf16x8 o;
        o[0] = f2bf(v0.x); o[1] = f2bf(v0.y); o[2] = f2bf(v0.z); o[3] = f2bf(v0.w);
        o[4] = f2bf(v1.x); o[5] = f2bf(v1.y); o[6] = f2bf(v1.z); o[7] = f2bf(v1.w);
        af[i] = o;
      }
#pragma unroll
      for (int j = 0; j < 2; ++j) {
        int rr = wc * 32 + j * 16 + l15;
        int g = s * 4 + lk;
        int byte = rr * 512 + ((g * 16) ^ ((rr & 7) << 4));
        bfr[j] = *(bf16x8*)(Bs + byte);
      }
      (void)swzmask;
      (void)bbyte;
#pragma unroll
      for (int i = 0; i < AM; ++i)
#pragma unroll
        for (int j = 0; j < 2; ++j)
          acc[i][j] = __builtin_amdgcn_mfma_f32_16x16x32_bf16(af[i], bfr[j], acc[i][j], 0, 0, 0);
    }
  }

  const int colb = nb * 64 + wc * 32 + l15;
#pragma unroll
  for (int i = 0; i < AM; ++i) {
#pragma unroll
    for (int r = 0; r < 4; ++r) {
      int grow = m0 + wr * WMT + i * 16 + lk * 4 + r;
      if (grow >= M) continue;
      float mfac = 1.f;
      if (VMASK) mfac = vmask[(size_t)(grow & 7) * Srows + (grow >> 3)] ? 0.f : 1.f;
#pragma unroll
      for (int j = 0; j < 2; ++j) {
        int col = colb + j * 16;
        float v = acc[i][j][r] + bias[col];
        if (VMASK) v *= mfac;
        if (RELU) v = fmaxf(v, 0.f);
        if (OBF16)
          ((__hip_bfloat16*)C)[(size_t)grow * N + col] = __float2bfloat16(v);
        else
          ((float*)C)[(size_t)grow * N + col] = v;
      }
    }
  }
}

// ---------------- self-attention, flash-style (fp32) ----------------
__global__ __launch_bounds__(256) void attn_kernel(const float* __restrict__ cqk,
                                                   const float* __restrict__ cv,
                                                   float* __restrict__ out) {
  __shared__ float Ks[NQ][32];
  __shared__ float Vs[NQ][32];
  const int b = blockIdx.x, h = blockIdx.y, qt = blockIdx.z;
  const int tid = threadIdx.x;
  for (int i = tid; i < NQ * 8; i += 256) {
    int qi = i >> 3, c4 = (i & 7) * 4;
    *(float4*)&Ks[qi][c4] = *(const float4*)&cqk[((size_t)(qi * 8 + b)) * 512 + 256 + h * 32 + c4];
    *(float4*)&Vs[qi][c4] = *(const float4*)&cv[((size_t)(qi * 8 + b)) * 256 + h * 32 + c4];
  }
  __syncthreads();
  const int row = qt * 64 + (tid >> 2);
  const int qr = tid & 3;
  if (row >= NQ) return;
  float qv[8];
  const float* qptr = &cqk[((size_t)(row * 8 + b)) * 512 + h * 32 + qr * 8];
  *(float4*)&qv[0] = *(const float4*)&qptr[0];
  *(float4*)&qv[4] = *(const float4*)&qptr[4];
  const float scale = 0.17677669529663687f;
  float m = -3.0e38f, l = 0.f;
  float acc[8] = {0.f, 0.f, 0.f, 0.f, 0.f, 0.f, 0.f, 0.f};
  for (int k = 0; k < NQ; ++k) {
    const float* kr = &Ks[k][qr * 8];
    float p = 0.f;
#pragma unroll
    for (int j = 0; j < 8; ++j) p = fmaf(qv[j], kr[j], p);
    p += __shfl_xor(p, 1, 4);
    p += __shfl_xor(p, 2, 4);
    float s = p * scale;
    float mn = fmaxf(m, s);
    float corr = __expf(m - mn);
    float e = __expf(s - mn);
    l = l * corr + e;
    const float* vr = &Vs[k][qr * 8];
#pragma unroll
    for (int j = 0; j < 8; ++j) acc[j] = fmaf(acc[j], corr, e * vr[j]);
    m = mn;
  }
  float inv = 1.f / l;
  float* op = &out[((size_t)(row * 8 + b)) * 256 + h * 32 + qr * 8];
#pragma unroll
  for (int j = 0; j < 8; ++j) op[j] = acc[j] * inv;
}

// ---------------- residual + layernorm ----------------
__global__ __launch_bounds__(256) void resid_ln_kernel(const float* __restrict__ X,
                                                       const float* __restrict__ R,
                                                       const float* __restrict__ g,
                                                       const float* __restrict__ be,
                                                       const float* __restrict__ addmask,
                                                       float* __restrict__ out,
                                                       float* __restrict__ out2) {
  const int r = blockIdx.x, c = threadIdx.x;
  const size_t i = (size_t)r * 256 + c;
  float x = X[i] + R[i];
  float s = x;
#pragma unroll
  for (int o = 32; o; o >>= 1) s += __shfl_xor(s, o, 64);
  __shared__ float sm[4], sv[4];
  const int w = c >> 6;
  if ((c & 63) == 0) sm[w] = s;
  __syncthreads();
  float mu = (sm[0] + sm[1] + sm[2] + sm[3]) * (1.f / 256.f);
  float d = x - mu;
  float v = d * d;
#pragma unroll
  for (int o = 32; o; o >>= 1) v += __shfl_xor(v, o, 64);
  if ((c & 63) == 0) sv[w] = v;
  __syncthreads();
  float var = (sv[0] + sv[1] + sv[2] + sv[3]) * (1.f / 256.f);
  float y = d * (1.f / sqrtf(var + 1e-5f)) * g[c] + be[c];
  out[i] = y;
  if (out2) out2[i] = y + addmask[i];
}

// ---------------- multi-scale deformable sampling (value in bf16) ----------------
__global__ __launch_bounds__(256) void deform_kernel(const unsigned short* __restrict__ value,
                                                     const float* __restrict__ off,
                                                     const float* __restrict__ awl,
                                                     const float* __restrict__ bbox,
                                                     const int* __restrict__ spatial,
                                                     const int* __restrict__ lstart,
                                                     float* __restrict__ out, int S) {
  __shared__ int sH[4], sW[4], sL[4];
  __shared__ float sbb[4];
  const int r = blockIdx.x;  // q*8+b
  const int b = r & 7;
  const int tid = threadIdx.x;
  if (tid < 4) {
    sH[tid] = spatial[tid * 2];
    sW[tid] = spatial[tid * 2 + 1];
    sL[tid] = lstart[tid];
    sbb[tid] = bbox[(size_t)r * 4 + tid];
  }
  __syncthreads();
  const float cx = sbb[0], cy = sbb[1], bw = sbb[2], bh = sbb[3];
  float ox = off[(size_t)r * 512 + (size_t)tid * 2];
  float oy = off[(size_t)r * 512 + (size_t)tid * 2 + 1];
  float a = awl[(size_t)r * 256 + tid];
  float mx = a;
#pragma unroll
  for (int o = 16; o; o >>= 1) mx = fmaxf(mx, __shfl_xor(mx, o, 32));
  float e = __expf(a - mx);
  float ssum = e;
#pragma unroll
  for (int o = 16; o; o >>= 1) ssum += __shfl_xor(ssum, o, 32);
  float myaw = e / ssum;

  float acc = 0.f;
  const size_t vb = (size_t)b * 256 + (size_t)tid;
  for (int lp = 0; lp < 32; ++lp) {
    const int l = lp >> 3;
    float bx = __shfl(ox, lp, 32);
    float by = __shfl(oy, lp, 32);
    float alp = __shfl(myaw, lp, 32);
    const float Wf = (float)sW[l], Hf = (float)sH[l];
    const int ls = sL[l], Wi = sW[l];
    float lx = cx + bx * 0.0625f * bw;
    float ly = cy + by * 0.0625f * bh;
    float x = lx * Wf - 0.5f;
    float y = ly * Hf - 0.5f;
    float x0 = floorf(x), y0 = floorf(y);
    float fx = x - x0, fy = y - y0;
    float tap = 0.f;
#pragma unroll
    for (int t = 0; t < 4; ++t) {
      float xi = x0 + (float)(t & 1);
      float yi = y0 + (float)(t >> 1);
      if (xi >= 0.f && yi >= 0.f && xi < Wf && yi < Hf) {
        float wx = (t & 1) ? fx : (1.f - fx);
        float wy = (t >> 1) ? fy : (1.f - fy);
        int idx = ls + (int)yi * Wi + (int)xi;
        tap = fmaf(wx * wy, bf2f(value[(size_t)idx * 2048 + vb]), tap);
      }
    }
    acc = fmaf(alp, tap, acc);
  }
  out[(size_t)r * 256 + tid] = acc;
}

extern "C" void kernel_launch(void* const* d_in, const int* in_sizes, int n_in, void* d_out,
                              int out_size, void* d_ws, size_t ws_size, hipStream_t stream) {
  (void)n_in; (void)out_size; (void)ws_size;
  const float* tgt = (const float*)d_in[0];
  const float* qmask = (const float*)d_in[1];
  const float* bbox = (const float*)d_in[2];
  const float* memory = (const float*)d_in[4];
  const float* ipw = (const float*)d_in[5];
  const float* ipb = (const float*)d_in[6];
  const float* osw = (const float*)d_in[7];
  const float* osb = (const float*)d_in[8];
  const float* n2g = (const float*)d_in[9];
  const float* n2b = (const float*)d_in[10];
  const float* vw = (const float*)d_in[11];
  const float* vbi = (const float*)d_in[12];
  const float* ow = (const float*)d_in[13];
  const float* ob = (const float*)d_in[14];
  const float* aww = (const float*)d_in[15];
  const float* awb = (const float*)d_in[16];
  const float* ocw = (const float*)d_in[17];
  const float* ocb = (const float*)d_in[18];
  const float* n1g = (const float*)d_in[19];
  const float* n1b = (const float*)d_in[20];
  const float* l1w = (const float*)d_in[21];
  const float* l1b = (const float*)d_in[22];
  const float* l2w = (const float*)d_in[23];
  const float* l2b = (const float*)d_in[24];
  const float* n3g = (const float*)d_in[25];
  const float* n3b = (const float*)d_in[26];
  const unsigned char* kpmask = (const unsigned char*)d_in[27];
  const int* spatial = (const int*)d_in[28];
  const int* lstart = (const int*)d_in[29];
  float* out = (float*)d_out;

  const int S = in_sizes[4] / (BSZ * DIM);  // 13294
  const int Mv = S * BSZ;                   // 106352

  float* ws = (float*)d_ws;
  size_t o = 0;
  unsigned short* value = (unsigned short*)(ws + o); o += (size_t)Mv * DIM / 2;  // bf16
  float* qsum = ws + o; o += (size_t)ROWS * DIM;
  float* cqk = ws + o; o += (size_t)ROWS * 512;
  float* cv = ws + o; o += (size_t)ROWS * DIM;
  float* sraw = ws + o; o += (size_t)ROWS * DIM;
  float* proj = ws + o; o += (size_t)ROWS * DIM;
  float* tgt2 = ws + o; o += (size_t)ROWS * DIM;
  float* q2 = ws + o; o += (size_t)ROWS * DIM;
  float* tgt3 = ws + o; o += (size_t)ROWS * DIM;
  float* ffn1 = ws + o; o += (size_t)ROWS * 1024;
  // bf16 swizzled weights
  unsigned short* wz = (unsigned short*)(ws + o);
  unsigned short* ipw_z = wz;                 // 768*256
  unsigned short* osw_z = ipw_z + 768 * 256;  // 256*256
  unsigned short* vw_z  = osw_z + 256 * 256;
  unsigned short* ow_z  = vw_z + 256 * 256;   // 512*256
  unsigned short* aww_z = ow_z + 512 * 256;   // 256*256
  unsigned short* ocw_z = aww_z + 256 * 256;  // 256*256
  unsigned short* l1w_z = ocw_z + 256 * 256;  // 1024*256
  unsigned short* l2w_z = l1w_z + 1024 * 256; // 256*1024

  // 0. convert all weights to bf16 swizzled tiles (one launch)
  WPack P;
  int gs = 0;
  auto ent = [&](int idx, const float* s, unsigned short* d, int N_, int K_) {
    P.e[idx] = {s, d, K_, gs};
    gs += N_ * K_ / 8;
  };
  ent(0, ipw, ipw_z, 768, 256);
  ent(1, osw, osw_z, 256, 256);
  ent(2, vw, vw_z, 256, 256);
  ent(3, ow, ow_z, 512, 256);
  ent(4, aww, aww_z, 256, 256);
  ent(5, ocw, ocw_z, 256, 256);
  ent(6, l1w, l1w_z, 1024, 256);
  ent(7, l2w, l2w_z, 256, 1024);
  P.total = gs;
  wconv_kernel<<<dim3((gs + 255) / 256), 256, 0, stream>>>(P);

  const int MB = (ROWS + 63) / 64;  // 38

  // 1. qsum = tgt + query_mask
  add4_kernel<<<dim3((ROWS * DIM / 4 + 255) / 256), 256, 0, stream>>>(
      (const float4*)tgt, (const float4*)qmask, (float4*)qsum, ROWS * DIM / 4);
  // 2. q/k projection (N=512)
  mgemm2<64, false, false, false><<<dim3(8, MB), 256, 0, stream>>>(
      qsum, ipw_z, ipb, cqk, ROWS, 512, DIM, nullptr, 0);
  // 3. v projection (tiles 8..11 of ipw)
  mgemm2<64, false, false, false><<<dim3(4, MB), 256, 0, stream>>>(
      tgt, ipw_z + 8 * 16384, ipb + 512, cv, ROWS, 256, DIM, nullptr, 0);
  // 4. self-attention
  attn_kernel<<<dim3(BSZ, NHEAD, (NQ + 63) / 64), 256, 0, stream>>>(cqk, cv, sraw);
  // 5. out_sa projection
  mgemm2<64, false, false, false><<<dim3(4, MB), 256, 0, stream>>>(
      sraw, osw_z, osb, proj, ROWS, 256, DIM, nullptr, 0);
  // 6. tgt2 = LN(tgt + sa), q2 = tgt2 + query_mask
  resid_ln_kernel<<<ROWS, 256, 0, stream>>>(proj, tgt, n2g, n2b, qmask, tgt2, q2);
  // 7. value projection (masked, bf16 out)
  mgemm2<128, false, true, true><<<dim3(4, (Mv + 127) / 128), 256, 0, stream>>>(
      memory, vw_z, vbi, value, Mv, 256, DIM, kpmask, S);
  // 8. offsets projection (N=512)
  mgemm2<64, false, false, false><<<dim3(8, MB), 256, 0, stream>>>(
      q2, ow_z, ob, cqk, ROWS, 512, DIM, nullptr, 0);
  // 9. attention-weight logits (N=256)
  mgemm2<64, false, false, false><<<dim3(4, MB), 256, 0, stream>>>(
      q2, aww_z, awb, cv, ROWS, 256, DIM, nullptr, 0);
  // 10. deformable sampling
  deform_kernel<<<ROWS, 256, 0, stream>>>(value, cqk, cv, bbox, spatial, lstart, sraw, S);
  // 11. out_ca projection
  mgemm2<64, false, false, false><<<dim3(4, MB), 256, 0, stream>>>(
      sraw, ocw_z, ocb, proj, ROWS, 256, DIM, nullptr, 0);
  // 12. tgt3 = LN(tgt2 + ca)
  resid_ln_kernel<<<ROWS, 256, 0, stream>>>(proj, tgt2, n1g, n1b, nullptr, tgt3, nullptr);
  // 13. FFN lin1 + relu (N=1024)
  mgemm2<64, true, false, false><<<dim3(16, MB), 256, 0, stream>>>(
      tgt3, l1w_z, l1b, ffn1, ROWS, 1024, DIM, nullptr, 0);
  // 14. FFN lin2 (K=1024)
  mgemm2<64, false, false, false><<<dim3(4, MB), 256, 0, stream>>>(
      ffn1, l2w_z, l2b, proj, ROWS, 256, 1024, nullptr, 0);
  // 15. out = LN(tgt3 + ffn)
  resid_ln_kernel<<<ROWS, 256, 0, stream>>>(proj, tgt3, n3g, n3b, nullptr, out, nullptr);
}

// Round 5
// 425.751 us; speedup vs baseline: 1.3006x; 1.3006x over previous
//
#include <hip/hip_runtime.h>
#include <hip/hip_bf16.h>
#include <math.h>

#define NQ 300
#define BSZ 8
#define DIM 256
#define NHEAD 8
#define ROWS 2400  // NQ*BSZ

typedef __attribute__((ext_vector_type(8))) short bf16x8;
typedef __attribute__((ext_vector_type(4))) float f32x4;

__device__ inline short f2bf(float f) {
  __hip_bfloat16 h = __float2bfloat16(f);
  return *reinterpret_cast<short*>(&h);
}
__device__ inline float bf2f(unsigned short u) {
  union { unsigned u; float f; } c;
  c.u = ((unsigned)u) << 16;
  return c.f;
}

// global->LDS 16B direct copy. gsrc includes the lane's 16B offset; ldst is the
// wave-uniform base (HW writes lane i at ldst + i*16).
#if __has_builtin(__builtin_amdgcn_global_load_lds)
__device__ inline void gld16(const void* gsrc, void* ldst, int lane) {
  (void)lane;
  auto g = (const __attribute__((address_space(1))) unsigned int*)gsrc;
  auto l = (__attribute__((address_space(3))) unsigned int*)ldst;
  __builtin_amdgcn_global_load_lds(g, l, 16, 0, 0);
}
#else
__device__ inline void gld16(const void* gsrc, void* ldst, int lane) {
  ((float4*)ldst)[lane] = *(const float4*)gsrc;
}
#endif

// ---------------- one-shot weight conversion fp32 -> bf16 IMG64 ----------------
// IMG64: per (nb64, c) an 8KB block = 64 rows x 64k bf16; within: byte(rr,k-gran g) =
// rr*128 + ((g*16) ^ ((rr&7)<<4)). GEMM stages a block with a LINEAR gld16 copy and
// reads with the same XOR (both-sides rule #21).
struct WEntry { const float* src; unsigned short* dst; int K; int gstart; };
struct WPack { WEntry e[8]; int total; };
__global__ __launch_bounds__(256) void wconv_kernel(WPack P) {
  int g = blockIdx.x * 256 + threadIdx.x;
  if (g >= P.total) return;
  int i = 0;
  while (i < 7 && g >= P.e[i + 1].gstart) ++i;
  const float* src = P.e[i].src;
  unsigned short* dst = P.e[i].dst;
  const int K = P.e[i].K;
  int gl = g - P.e[i].gstart;
  int gpr = K >> 3;
  int r = gl / gpr, gk = gl - r * gpr;
  int nb = r >> 6, rr = r & 63;
  int c = gk >> 3, g8 = gk & 7;
  const float* s = src + (size_t)r * K + gk * 8;
  float4 v0 = *(const float4*)s, v1 = *(const float4*)(s + 4);
  bf16x8 o;
  o[0] = f2bf(v0.x); o[1] = f2bf(v0.y); o[2] = f2bf(v0.z); o[3] = f2bf(v0.w);
  o[4] = f2bf(v1.x); o[5] = f2bf(v1.y); o[6] = f2bf(v1.z); o[7] = f2bf(v1.w);
  size_t byte = ((size_t)(nb * (K >> 6) + c) * 64 + rr) * 128 + ((g8 * 16) ^ ((rr & 7) << 4));
  *(bf16x8*)((char*)dst + byte) = o;
}

__global__ void bias_cat(const float* __restrict__ a, const float* __restrict__ b,
                         float* __restrict__ o) {
  int t = blockIdx.x * 256 + threadIdx.x;
  if (t < 512) o[t] = a[t];
  else if (t < 768) o[t] = b[t - 512];
}

// ---------------- big GEMM: value = memory(fp32) @ vw^T, m97 structure ----------------
// BM=128, BN=128, K=N=256. A staged fp32 via gld16 with pre-swizzled global lane addr
// (32B-granule XOR swizzle), converted to bf16 on LDS read. B staged from IMG64 linearly.
template <bool VMASK>
__global__ __launch_bounds__(256) void vgemm(const float* __restrict__ A,
                                             const unsigned short* __restrict__ Wz,
                                             const float* __restrict__ bias,
                                             __hip_bfloat16* __restrict__ C, int M,
                                             const unsigned char* __restrict__ vmask,
                                             int Srows) {
  __shared__ char As[32768];   // 128 rows x 256B fp32, 32B-granule swizzled
  __shared__ char Bsh[16384];  // 2 IMG64 blocks (128 weight rows x 64k bf16)
  const int tid = threadIdx.x, lane = tid & 63, wid = tid >> 6;
  const int wr = wid >> 1, wc = wid & 1;
  const int nb = blockIdx.x;
  const int m0 = blockIdx.y * 128;
  const int l15 = lane & 15, lk = lane >> 4;

  f32x4 acc[4][4];
#pragma unroll
  for (int i = 0; i < 4; ++i)
#pragma unroll
    for (int j = 0; j < 4; ++j) acc[i][j] = {0.f, 0.f, 0.f, 0.f};

  // A stage source addresses (8 x 1KB chunks per wave); swizzle folded into gg
  const float* asrc[8];
#pragma unroll
  for (int i = 0; i < 8; ++i) {
    int ach = wid * 8 + i;
    int rr = ach * 4 + lk;
    int gg = ((((l15 >> 1) ^ (rr & 7)) << 1) | (l15 & 1));
    int rrg = m0 + rr;
    if (rrg > M - 1) rrg = M - 1;
    asrc[i] = A + (size_t)rrg * 256 + gg * 4;
  }

  for (int c = 0; c < 4; ++c) {
    __syncthreads();
#pragma unroll
    for (int i = 0; i < 8; ++i) gld16(asrc[i] + c * 64, As + (wid * 8 + i) * 1024, lane);
#pragma unroll
    for (int i = 0; i < 4; ++i) {
      int bch = wid * 4 + i;
      const char* src = (const char*)Wz +
                        ((size_t)((2 * nb + (bch >> 3)) * 4 + c)) * 8192 +
                        (bch & 7) * 1024 + lane * 16;
      gld16(src, Bsh + bch * 1024, lane);
    }
    __syncthreads();
#pragma unroll
    for (int kk = 0; kk < 2; ++kk) {
      bf16x8 af[4], bfr[4];
#pragma unroll
      for (int i = 0; i < 4; ++i) {
        int rr = wr * 64 + i * 16 + l15;
        int g32 = kk * 4 + lk;
        int byte = rr * 256 + ((g32 * 32) ^ ((rr & 7) << 5));
        f32x4 lo = *(f32x4*)(As + byte);
        f32x4 hi = *(f32x4*)(As + byte + 16);
        bf16x8 o;
        o[0] = f2bf(lo[0]); o[1] = f2bf(lo[1]); o[2] = f2bf(lo[2]); o[3] = f2bf(lo[3]);
        o[4] = f2bf(hi[0]); o[5] = f2bf(hi[1]); o[6] = f2bf(hi[2]); o[7] = f2bf(hi[3]);
        af[i] = o;
      }
#pragma unroll
      for (int j = 0; j < 4; ++j) {
        int rr = wc * 64 + j * 16 + l15;
        int g = kk * 4 + lk;
        int byte = (rr >> 6) * 8192 + (rr & 63) * 128 + ((g * 16) ^ ((rr & 7) << 4));
        bfr[j] = *(bf16x8*)(Bsh + byte);
      }
#pragma unroll
      for (int i = 0; i < 4; ++i)
#pragma unroll
        for (int j = 0; j < 4; ++j)
          acc[i][j] = __builtin_amdgcn_mfma_f32_16x16x32_bf16(af[i], bfr[j], acc[i][j], 0, 0, 0);
    }
  }

#pragma unroll
  for (int i = 0; i < 4; ++i) {
#pragma unroll
    for (int r = 0; r < 4; ++r) {
      int row = m0 + wr * 64 + i * 16 + lk * 4 + r;
      if (row >= M) continue;
      float mfac = 1.f;
      if (VMASK) mfac = vmask[(size_t)(row & 7) * Srows + (row >> 3)] ? 0.f : 1.f;
#pragma unroll
      for (int j = 0; j < 4; ++j) {
        int col = nb * 128 + wc * 64 + j * 16 + l15;
        float v = acc[i][j][r] + bias[col];
        if (VMASK) v *= mfac;
        C[(size_t)row * 256 + col] = __float2bfloat16(v);
      }
    }
  }
}

// ---------------- small GEMM: C = A(fp32)@Wz^T + bias; BN=64 ----------------
// A reg-staged to bf16 IMG in LDS (optionally A+Am fused); B via gld16 linear copy.
// QKV: nb<8 -> out C0 (stride 512, A+Am); nb>=8 -> out C1 (stride 256, plain A).
template <int BM, bool RELU, bool ADDM, bool QKV>
__global__ __launch_bounds__(256) void sgemm(const float* __restrict__ A,
                                             const float* __restrict__ Am,
                                             const unsigned short* __restrict__ Wz,
                                             const float* __restrict__ bias,
                                             float* __restrict__ C0, float* __restrict__ C1,
                                             int M, int Ns, int K) {
  constexpr int WMT = BM / 2, AM = WMT / 16;
  __shared__ char As[BM * 128];
  __shared__ char Bsh[8192];
  const int tid = threadIdx.x, lane = tid & 63, wid = tid >> 6;
  const int wr = wid >> 1, wc = wid & 1;
  const int nb = blockIdx.x, m0 = blockIdx.y * BM;
  const int l15 = lane & 15, lk = lane >> 4;
  const bool useM = QKV ? (nb < 8) : ADDM;

  f32x4 acc[AM][2];
#pragma unroll
  for (int i = 0; i < AM; ++i)
#pragma unroll
    for (int j = 0; j < 2; ++j) acc[i][j] = {0.f, 0.f, 0.f, 0.f};

  const int nch = K >> 6;
  for (int c = 0; c < nch; ++c) {
    __syncthreads();
    // stage A: each thread BM/32 granules (32B fp32 -> 16B bf16)
#pragma unroll
    for (int j = 0; j < BM / 32; ++j) {
      int gi = tid * (BM / 32) + j;
      int rr = gi >> 3, g = gi & 7;
      int rg = m0 + rr;
      float4 v0 = make_float4(0.f, 0.f, 0.f, 0.f), v1 = v0;
      if (rg < M) {
        const float* p = A + (size_t)rg * K + c * 64 + g * 8;
        v0 = *(const float4*)p;
        v1 = *(const float4*)(p + 4);
        if (useM) {
          const float* q = Am + (size_t)rg * K + c * 64 + g * 8;
          float4 w0 = *(const float4*)q, w1 = *(const float4*)(q + 4);
          v0.x += w0.x; v0.y += w0.y; v0.z += w0.z; v0.w += w0.w;
          v1.x += w1.x; v1.y += w1.y; v1.z += w1.z; v1.w += w1.w;
        }
      }
      bf16x8 o;
      o[0] = f2bf(v0.x); o[1] = f2bf(v0.y); o[2] = f2bf(v0.z); o[3] = f2bf(v0.w);
      o[4] = f2bf(v1.x); o[5] = f2bf(v1.y); o[6] = f2bf(v1.z); o[7] = f2bf(v1.w);
      int byte = rr * 128 + ((g * 16) ^ ((rr & 7) << 4));
      *(bf16x8*)(As + byte) = o;
    }
    // stage B: 8KB linear copy of pre-swizzled IMG64 block
#pragma unroll
    for (int i = 0; i < 2; ++i) {
      const char* src = (const char*)Wz + ((size_t)(nb * nch + c)) * 8192 +
                        wid * 2048 + i * 1024 + lane * 16;
      gld16(src, Bsh + wid * 2048 + i * 1024, lane);
    }
    __syncthreads();
#pragma unroll
    for (int kk = 0; kk < 2; ++kk) {
      bf16x8 af[AM], bfr[2];
#pragma unroll
      for (int i = 0; i < AM; ++i) {
        int rr = wr * WMT + i * 16 + l15;
        int byte = rr * 128 + (((kk * 4 + lk) * 16) ^ ((rr & 7) << 4));
        af[i] = *(bf16x8*)(As + byte);
      }
#pragma unroll
      for (int j = 0; j < 2; ++j) {
        int rr = wc * 32 + j * 16 + l15;
        int byte = rr * 128 + (((kk * 4 + lk) * 16) ^ ((rr & 7) << 4));
        bfr[j] = *(bf16x8*)(Bsh + byte);
      }
#pragma unroll
      for (int i = 0; i < AM; ++i)
#pragma unroll
        for (int j = 0; j < 2; ++j)
          acc[i][j] = __builtin_amdgcn_mfma_f32_16x16x32_bf16(af[i], bfr[j], acc[i][j], 0, 0, 0);
    }
  }

  float* outp;
  int ostride, ocol0;
  if (QKV) {
    if (nb < 8) { outp = C0; ostride = 512; ocol0 = nb * 64; }
    else        { outp = C1; ostride = 256; ocol0 = (nb - 8) * 64; }
  } else {
    outp = C0; ostride = Ns; ocol0 = nb * 64;
  }
#pragma unroll
  for (int i = 0; i < AM; ++i) {
#pragma unroll
    for (int r = 0; r < 4; ++r) {
      int row = m0 + wr * WMT + i * 16 + lk * 4 + r;
      if (row >= M) continue;
#pragma unroll
      for (int j = 0; j < 2; ++j) {
        int cl = wc * 32 + j * 16 + l15;
        float v = acc[i][j][r] + bias[nb * 64 + cl];
        if (RELU) v = fmaxf(v, 0.f);
        outp[(size_t)row * ostride + ocol0 + cl] = v;
      }
    }
  }
}

// ---------------- self-attention, flash-style (fp32) ----------------
__global__ __launch_bounds__(256) void attn_kernel(const float* __restrict__ cqk,
                                                   const float* __restrict__ cv,
                                                   float* __restrict__ out) {
  __shared__ float Ks[NQ][32];
  __shared__ float Vs[NQ][32];
  const int b = blockIdx.x, h = blockIdx.y, qt = blockIdx.z;
  const int tid = threadIdx.x;
  for (int i = tid; i < NQ * 8; i += 256) {
    int qi = i >> 3, c4 = (i & 7) * 4;
    *(float4*)&Ks[qi][c4] = *(const float4*)&cqk[((size_t)(qi * 8 + b)) * 512 + 256 + h * 32 + c4];
    *(float4*)&Vs[qi][c4] = *(const float4*)&cv[((size_t)(qi * 8 + b)) * 256 + h * 32 + c4];
  }
  __syncthreads();
  const int row = qt * 64 + (tid >> 2);
  const int qr = tid & 3;
  if (row >= NQ) return;
  float qv[8];
  const float* qptr = &cqk[((size_t)(row * 8 + b)) * 512 + h * 32 + qr * 8];
  *(float4*)&qv[0] = *(const float4*)&qptr[0];
  *(float4*)&qv[4] = *(const float4*)&qptr[4];
  const float scale = 0.17677669529663687f;
  float m = -3.0e38f, l = 0.f;
  float acc[8] = {0.f, 0.f, 0.f, 0.f, 0.f, 0.f, 0.f, 0.f};
  for (int k = 0; k < NQ; ++k) {
    const float* kr = &Ks[k][qr * 8];
    float p = 0.f;
#pragma unroll
    for (int j = 0; j < 8; ++j) p = fmaf(qv[j], kr[j], p);
    p += __shfl_xor(p, 1, 4);
    p += __shfl_xor(p, 2, 4);
    float s = p * scale;
    float mn = fmaxf(m, s);
    float corr = __expf(m - mn);
    float e = __expf(s - mn);
    l = l * corr + e;
    const float* vr = &Vs[k][qr * 8];
#pragma unroll
    for (int j = 0; j < 8; ++j) acc[j] = fmaf(acc[j], corr, e * vr[j]);
    m = mn;
  }
  float inv = 1.f / l;
  float* op = &out[((size_t)(row * 8 + b)) * 256 + h * 32 + qr * 8];
#pragma unroll
  for (int j = 0; j < 8; ++j) op[j] = acc[j] * inv;
}

// ---------------- residual + layernorm ----------------
__global__ __launch_bounds__(256) void resid_ln_kernel(const float* __restrict__ X,
                                                       const float* __restrict__ R,
                                                       const float* __restrict__ g,
                                                       const float* __restrict__ be,
                                                       float* __restrict__ out) {
  const int r = blockIdx.x, c = threadIdx.x;
  const size_t i = (size_t)r * 256 + c;
  float x = X[i] + R[i];
  float s = x;
#pragma unroll
  for (int o = 32; o; o >>= 1) s += __shfl_xor(s, o, 64);
  __shared__ float sm[4], sv[4];
  const int w = c >> 6;
  if ((c & 63) == 0) sm[w] = s;
  __syncthreads();
  float mu = (sm[0] + sm[1] + sm[2] + sm[3]) * (1.f / 256.f);
  float d = x - mu;
  float v = d * d;
#pragma unroll
  for (int o = 32; o; o >>= 1) v += __shfl_xor(v, o, 64);
  if ((c & 63) == 0) sv[w] = v;
  __syncthreads();
  float var = (sv[0] + sv[1] + sv[2] + sv[3]) * (1.f / 256.f);
  out[i] = d * (1.f / sqrtf(var + 1e-5f)) * g[c] + be[c];
}

// ---------------- multi-scale deformable sampling (value bf16, offaw fused buf) ----------------
__global__ __launch_bounds__(256) void deform_kernel(const unsigned short* __restrict__ value,
                                                     const float* __restrict__ offaw,
                                                     const float* __restrict__ bbox,
                                                     const int* __restrict__ spatial,
                                                     const int* __restrict__ lstart,
                                                     float* __restrict__ out, int S) {
  __shared__ int sH[4], sW[4], sL[4];
  __shared__ float sbb[4];
  const int r = blockIdx.x;  // q*8+b
  const int b = r & 7;
  const int tid = threadIdx.x;
  if (tid < 4) {
    sH[tid] = spatial[tid * 2];
    sW[tid] = spatial[tid * 2 + 1];
    sL[tid] = lstart[tid];
    sbb[tid] = bbox[(size_t)r * 4 + tid];
  }
  __syncthreads();
  const float cx = sbb[0], cy = sbb[1], bw = sbb[2], bh = sbb[3];
  float ox = offaw[(size_t)r * 768 + (size_t)tid * 2];
  float oy = offaw[(size_t)r * 768 + (size_t)tid * 2 + 1];
  float a = offaw[(size_t)r * 768 + 512 + tid];
  float mx = a;
#pragma unroll
  for (int o = 16; o; o >>= 1) mx = fmaxf(mx, __shfl_xor(mx, o, 32));
  float e = __expf(a - mx);
  float ssum = e;
#pragma unroll
  for (int o = 16; o; o >>= 1) ssum += __shfl_xor(ssum, o, 32);
  float myaw = e / ssum;

  float acc = 0.f;
  const size_t vb = (size_t)b * 256 + (size_t)tid;
  for (int lp = 0; lp < 32; ++lp) {
    const int l = lp >> 3;
    float bx = __shfl(ox, lp, 32);
    float by = __shfl(oy, lp, 32);
    float alp = __shfl(myaw, lp, 32);
    const float Wf = (float)sW[l], Hf = (float)sH[l];
    const int ls = sL[l], Wi = sW[l];
    float lx = cx + bx * 0.0625f * bw;
    float ly = cy + by * 0.0625f * bh;
    float x = lx * Wf - 0.5f;
    float y = ly * Hf - 0.5f;
    float x0 = floorf(x), y0 = floorf(y);
    float fx = x - x0, fy = y - y0;
    float tap = 0.f;
#pragma unroll
    for (int t = 0; t < 4; ++t) {
      float xi = x0 + (float)(t & 1);
      float yi = y0 + (float)(t >> 1);
      if (xi >= 0.f && yi >= 0.f && xi < Wf && yi < Hf) {
        float wx = (t & 1) ? fx : (1.f - fx);
        float wy = (t >> 1) ? fy : (1.f - fy);
        int idx = ls + (int)yi * Wi + (int)xi;
        tap = fmaf(wx * wy, bf2f(value[(size_t)idx * 2048 + vb]), tap);
      }
    }
    acc = fmaf(alp, tap, acc);
  }
  out[(size_t)r * 256 + tid] = acc;
}

extern "C" void kernel_launch(void* const* d_in, const int* in_sizes, int n_in, void* d_out,
                              int out_size, void* d_ws, size_t ws_size, hipStream_t stream) {
  (void)n_in; (void)out_size; (void)ws_size;
  const float* tgt = (const float*)d_in[0];
  const float* qmask = (const float*)d_in[1];
  const float* bbox = (const float*)d_in[2];
  const float* memory = (const float*)d_in[4];
  const float* ipw = (const float*)d_in[5];
  const float* ipb = (const float*)d_in[6];
  const float* osw = (const float*)d_in[7];
  const float* osb = (const float*)d_in[8];
  const float* n2g = (const float*)d_in[9];
  const float* n2b = (const float*)d_in[10];
  const float* vw = (const float*)d_in[11];
  const float* vbi = (const float*)d_in[12];
  const float* ow = (const float*)d_in[13];
  const float* ob = (const float*)d_in[14];
  const float* aww = (const float*)d_in[15];
  const float* awb = (const float*)d_in[16];
  const float* ocw = (const float*)d_in[17];
  const float* ocb = (const float*)d_in[18];
  const float* n1g = (const float*)d_in[19];
  const float* n1b = (const float*)d_in[20];
  const float* l1w = (const float*)d_in[21];
  const float* l1b = (const float*)d_in[22];
  const float* l2w = (const float*)d_in[23];
  const float* l2b = (const float*)d_in[24];
  const float* n3g = (const float*)d_in[25];
  const float* n3b = (const float*)d_in[26];
  const unsigned char* kpmask = (const unsigned char*)d_in[27];
  const int* spatial = (const int*)d_in[28];
  const int* lstart = (const int*)d_in[29];
  float* out = (float*)d_out;

  const int S = in_sizes[4] / (BSZ * DIM);  // 13294
  const int Mv = S * BSZ;                   // 106352

  float* ws = (float*)d_ws;
  size_t o = 0;
  unsigned short* value = (unsigned short*)(ws + o); o += (size_t)Mv * DIM / 2;  // bf16
  float* cqk = ws + o; o += (size_t)ROWS * 512;
  float* cv = ws + o; o += (size_t)ROWS * DIM;
  float* sraw = ws + o; o += (size_t)ROWS * DIM;
  float* proj = ws + o; o += (size_t)ROWS * DIM;
  float* tgt2 = ws + o; o += (size_t)ROWS * DIM;
  float* tgt3 = ws + o; o += (size_t)ROWS * DIM;
  float* ffn1 = ws + o; o += (size_t)ROWS * 1024;
  float* offaw = ws + o; o += (size_t)ROWS * 768;
  float* obaw = ws + o; o += 768;
  unsigned short* wz = (unsigned short*)(ws + o);
  unsigned short* ipw_z = wz;
  unsigned short* osw_z = ipw_z + 768 * 256;
  unsigned short* vw_z  = osw_z + 256 * 256;
  unsigned short* ow_z  = vw_z + 256 * 256;
  unsigned short* aww_z = ow_z + 512 * 256;   // must follow ow_z (concat N=768)
  unsigned short* ocw_z = aww_z + 256 * 256;
  unsigned short* l1w_z = ocw_z + 256 * 256;
  unsigned short* l2w_z = l1w_z + 1024 * 256;

  // 0. weights -> bf16 IMG64 (one launch) + bias concat
  WPack P;
  int gs = 0;
  auto ent = [&](int idx, const float* s, unsigned short* d, int N_, int K_) {
    P.e[idx] = {s, d, K_, gs};
    gs += N_ * K_ / 8;
  };
  ent(0, ipw, ipw_z, 768, 256);
  ent(1, osw, osw_z, 256, 256);
  ent(2, vw, vw_z, 256, 256);
  ent(3, ow, ow_z, 512, 256);
  ent(4, aww, aww_z, 256, 256);
  ent(5, ocw, ocw_z, 256, 256);
  ent(6, l1w, l1w_z, 1024, 256);
  ent(7, l2w, l2w_z, 256, 1024);
  P.total = gs;
  wconv_kernel<<<dim3((gs + 255) / 256), 256, 0, stream>>>(P);
  bias_cat<<<dim3(3), 256, 0, stream>>>(ob, awb, obaw);

  // 1. fused add + q/k/v projections (dual-A, dual-out)
  sgemm<64, false, false, true><<<dim3(12, 38), 256, 0, stream>>>(
      tgt, qmask, ipw_z, ipb, cqk, cv, ROWS, 0, 256);
  // 2. self-attention
  attn_kernel<<<dim3(BSZ, NHEAD, (NQ + 63) / 64), 256, 0, stream>>>(cqk, cv, sraw);
  // 3. out_sa projection
  sgemm<32, false, false, false><<<dim3(4, 75), 256, 0, stream>>>(
      sraw, nullptr, osw_z, osb, proj, nullptr, ROWS, 256, 256);
  // 4. tgt2 = LN(tgt + sa)
  resid_ln_kernel<<<ROWS, 256, 0, stream>>>(proj, tgt, n2g, n2b, tgt2);
  // 5. value projection (big, masked, bf16 out)
  vgemm<true><<<dim3(2, (Mv + 127) / 128), 256, 0, stream>>>(
      memory, vw_z, vbi, (__hip_bfloat16*)value, Mv, kpmask, S);
  // 6. fused offsets+aw projections (A = tgt2 + qmask), N=768
  sgemm<64, false, true, false><<<dim3(12, 38), 256, 0, stream>>>(
      tgt2, qmask, ow_z, obaw, offaw, nullptr, ROWS, 768, 256);
  // 7. deformable sampling
  deform_kernel<<<ROWS, 256, 0, stream>>>(value, offaw, bbox, spatial, lstart, sraw, S);
  // 8. out_ca projection
  sgemm<32, false, false, false><<<dim3(4, 75), 256, 0, stream>>>(
      sraw, nullptr, ocw_z, ocb, proj, nullptr, ROWS, 256, 256);
  // 9. tgt3 = LN(tgt2 + ca)
  resid_ln_kernel<<<ROWS, 256, 0, stream>>>(proj, tgt2, n1g, n1b, tgt3);
  // 10. FFN lin1 + relu
  sgemm<64, true, false, false><<<dim3(16, 38), 256, 0, stream>>>(
      tgt3, nullptr, l1w_z, l1b, ffn1, nullptr, ROWS, 1024, 256);
  // 11. FFN lin2 (K=1024)
  sgemm<32, false, false, false><<<dim3(4, 75), 256, 0, stream>>>(
      ffn1, nullptr, l2w_z, l2b, proj, nullptr, ROWS, 256, 1024);
  // 12. out = LN(tgt3 + ffn)
  resid_ln_kernel<<<ROWS, 256, 0, stream>>>(proj, tgt3, n3g, n3b, out);
}